// Round 4
// baseline (69.718 us; speedup 1.0000x reference)
//
#include <hip/hip_runtime.h>
#include <math.h>

#define RADIUS 0.05f
#define NTHREADS 1024     // 16 waves/block, grid=256 -> 1 block/CU, minimum scan redundancy
#define TSZ      8        // 8x8 pixel tile (measured best vs 4x4: 69.5 vs 75.3 us)
#define NPIX     64       // pixels per tile
#define NSLICE   16       // point-slices per tile = waves per block
#define SPCAP   256       // per-tile candidate capacity (E~67; overflow P ~ e^-46)
#define HCAP    40        // per-pixel hit capacity (E=8, Poisson tail ~1e-18)
#define HSTR    41        // stride 41 dwords: 41 mod 32 = 9, gcd(9,32)=1 -> conflict-free

// One block = one 8x8 pixel tile, 1024 threads = 64 pixels x 16 point-slices.
// 256 blocks = minimum scan redundancy (round 1 showed 1024 blocks costs +4.8us).
// Phase 1: div-free cull, 4 points per 3 float4 loads (1 iteration/thread at N=4096).
// Prefetch: candidate features (cnt*2 float4s) issued to registers BEFORE phase 2;
//           loads stay in flight across phase 2 (no global ops there), landed into
//           LDS after -> phase 3 reads features from LDS, zero cold-HBM gather.
// Phase 2: sliced scan (16 slices), hits appended to per-pixel LDS lists (slot ids).
// Phase 3: 64 pixels on waves 0-3 lanes 0-15 (all 4 SIMDs run the serial tail).
__global__ __launch_bounds__(NTHREADS) void render_tiles(
    const float* __restrict__ points,    // [N,3] camera space
    const float* __restrict__ features,  // [N,8]
    float* __restrict__ out,             // [H,W,8]
    int N, int H, int W, int tiles_x)
{
    const float r2 = RADIUS * RADIUS;
    const float inv_r2 = 1.0f / r2;

    __shared__ float4 sp[SPCAP];          // (px, py, z, idx-as-float)
    __shared__ float4 s_feat[SPCAP * 2];  // candidate features, 2 float4 per slot
    __shared__ float  s_hz[NPIX * HSTR];
    __shared__ float  s_hd[NPIX * HSTR];
    __shared__ int    s_hi[NPIX * HSTR];  // candidate SLOT (not global id)
    __shared__ int    s_pcnt[NPIX];
    __shared__ int    s_cnt;

    const int tid = threadIdx.x;
    if (tid == 0) s_cnt = 0;
    if (tid < NPIX) s_pcnt[tid] = 0;
    __syncthreads();

    const int tile = blockIdx.x;
    const int tx = tile % tiles_x;
    const int ty = tile / tiles_x;
    const int x0i = tx * TSZ, y0i = ty * TSZ;
    const float sx = 2.0f / (float)W, sy = 2.0f / (float)H;
    // tile pixel-center NDC bounds, expanded by splat radius (conservative)
    const float bx0 = ((float)x0i + 0.5f) * sx - 1.0f - RADIUS;
    const float bx1 = ((float)(x0i + TSZ - 1) + 0.5f) * sx - 1.0f + RADIUS;
    const float by0 = ((float)y0i + 0.5f) * sy - 1.0f - RADIUS;
    const float by1 = ((float)(y0i + TSZ - 1) + 0.5f) * sy - 1.0f + RADIUS;

    // ---- Phase 1: vectorized div-free cull (px>=bx0 <=> x>=bx0*z since z>0) ----
    // 4 points = 48 B = 3 x float4; at N=4096/1024 threads: exactly 1 iter/thread.
    const float4* p4 = (const float4*)points;
    const int N4 = N & ~3;
    for (int i0 = tid * 4; i0 < N4; i0 += NTHREADS * 4) {
        const int q = 3 * (i0 >> 2);
        float4 a = p4[q + 0];
        float4 b = p4[q + 1];
        float4 c = p4[q + 2];
        const float xs_[4] = {a.x, a.w, b.z, c.y};
        const float ys_[4] = {a.y, b.x, b.w, c.z};
        const float zs_[4] = {a.z, b.y, c.x, c.w};
#pragma unroll
        for (int j = 0; j < 4; j++) {
            float x = xs_[j], y = ys_[j], z = zs_[j];
            bool keep = (z > 0.0f) & (x >= bx0 * z) & (x <= bx1 * z)
                                   & (y >= by0 * z) & (y <= by1 * z);
            if (keep) {
                float rz = __builtin_amdgcn_rcpf(z);   // ~1ulp; error << alpha threshold
                int pos = atomicAdd(&s_cnt, 1);
                if (pos < SPCAP)
                    sp[pos] = make_float4(x * rz, y * rz, z, __int_as_float(i0 + j));
            }
        }
    }
    // scalar tail (N % 4 != 0); no-op for N=4096
    for (int i = N4 + tid; i < N; i += NTHREADS) {
        float x = points[3 * i + 0];
        float y = points[3 * i + 1];
        float z = points[3 * i + 2];
        bool keep = (z > 0.0f) & (x >= bx0 * z) & (x <= bx1 * z)
                               & (y >= by0 * z) & (y <= by1 * z);
        if (keep) {
            float rz = __builtin_amdgcn_rcpf(z);
            int pos = atomicAdd(&s_cnt, 1);
            if (pos < SPCAP) sp[pos] = make_float4(x * rz, y * rz, z, __int_as_float(i));
        }
    }
    __syncthreads();
    const int cnt = min(s_cnt, SPCAP);

    // ---- Feature prefetch: issue now, land after phase 2 (latency hidden) ----
    float4 pf = make_float4(0.f, 0.f, 0.f, 0.f);
    int pfdst = -1;
    if (tid < cnt * 2) {                   // cnt*2 <= 512 <= NTHREADS
        const int slot = tid >> 1, half = tid & 1;
        const int gid = __float_as_int(sp[slot].w);
        pf = ((const float4*)features)[gid * 2 + half];
        pfdst = tid;
    }

    // ---- Phase 2: sliced scan, append hits per pixel (pipelined LDS reads) ----
    const int pxl = tid & 63;
    const int slice = tid >> 6;   // 0..15
    const int ix = x0i + (pxl & 7);
    const int iy = y0i + (pxl >> 3);
    const float gx = ((float)ix + 0.5f) * sx - 1.0f;
    const float gy = ((float)iy + 0.5f) * sy - 1.0f;

    int c = slice;
    if (c < cnt) {
        float4 q = sp[c];                 // broadcast across wave, conflict-free
        while (true) {
            int cn = c + NSLICE;
            bool more = cn < cnt;
            float4 qn = sp[more ? cn : slice];   // prefetch next before processing
            float dx = gx - q.x;
            float dy = gy - q.y;
            float d2 = dx * dx + dy * dy;
            if (d2 < r2) {
                int pos = atomicAdd(&s_pcnt[pxl], 1);
                if (pos < HCAP) {
                    s_hz[pxl * HSTR + pos] = q.z;
                    s_hd[pxl * HSTR + pos] = d2;
                    s_hi[pxl * HSTR + pos] = c;      // candidate slot, not global id
                }
            }
            if (!more) break;
            q = qn; c = cn;
        }
    }
    // land the prefetched features into LDS (waitcnt here, after phase-2 compute)
    if (pfdst >= 0) s_feat[pfdst] = pf;
    __syncthreads();

    // ---- Phase 3: per-pixel top-8 by depth + composite (features from LDS) ----
    // waves 0-3, lanes 0-15: 16 pixels/wave -> all 4 SIMDs run the serial tail.
    const int wv = tid >> 6;
    const int ln = tid & 63;
    if (wv < 4 && ln < 16) {
        const int p = wv * 16 + ln;       // 0..63
        const int m = min(s_pcnt[p], HCAP);
        float zk[8];
        int sk[8];
#pragma unroll
        for (int k = 0; k < 8; k++) { zk[k] = 3.0e38f; sk[k] = 0; }

        float z_next = s_hz[p * HSTR];              // safe: garbage if m==0, unused
        for (int i = 0; i < m; i++) {
            float z = z_next;
            z_next = s_hz[p * HSTR + i + 1];        // prefetch (i+1 <= HCAP, in-bounds)
            if (z < zk[7]) {
                int s = i;
#pragma unroll
                for (int k = 0; k < 8; k++) {
                    bool lt = z < zk[k];   // strict <, z distinct -> order-independent
                    float tz = zk[k];
                    int ts = sk[k];
                    if (lt) { zk[k] = z; sk[k] = s; z = tz; s = ts; }
                }
            }
        }

        float acc0 = 0.f, acc1 = 0.f, acc2 = 0.f, acc3 = 0.f;
        float acc4 = 0.f, acc5 = 0.f, acc6 = 0.f, acc7 = 0.f;
        float T = 1.0f;
#pragma unroll
        for (int k = 0; k < 8; k++) {
            if (zk[k] < 1.0e30f) {
                float d2 = s_hd[p * HSTR + sk[k]];
                int slot = s_hi[p * HSTR + sk[k]];
                float alpha = 1.0f - d2 * inv_r2;
                alpha = fminf(fmaxf(alpha, 0.0f), 1.0f);
                float w = alpha * T;
                T *= (1.0f - alpha);
                float4 f0 = s_feat[slot * 2 + 0];
                float4 f1 = s_feat[slot * 2 + 1];
                acc0 += w * f0.x; acc1 += w * f0.y; acc2 += w * f0.z; acc3 += w * f0.w;
                acc4 += w * f1.x; acc5 += w * f1.y; acc6 += w * f1.z; acc7 += w * f1.w;
            }
        }

        const int oix = x0i + (p & 7);
        const int oiy = y0i + (p >> 3);
        if (oix < W && oiy < H) {
            float4* o = (float4*)(out + (size_t)(oiy * W + oix) * 8);
            o[0] = make_float4(acc0, acc1, acc2, acc3);
            o[1] = make_float4(acc4, acc5, acc6, acc7);
        }
    }
}

extern "C" void kernel_launch(void* const* d_in, const int* in_sizes, int n_in,
                              void* d_out, int out_size, void* d_ws, size_t ws_size,
                              hipStream_t stream) {
    const float* points = (const float*)d_in[0];
    const float* features = (const float*)d_in[1];
    float* out = (float*)d_out;

    int N = in_sizes[0] / 3;                // 4096
    int C = in_sizes[1] / N;                // 8 (kernel assumes 8)
    int P = out_size / C;                   // 16384
    int H = (int)(sqrt((double)P) + 0.5);   // 128
    int W = H;
    int tiles_x = (W + TSZ - 1) / TSZ;      // 16
    int tiles_y = (H + TSZ - 1) / TSZ;      // 16

    render_tiles<<<tiles_x * tiles_y, NTHREADS, 0, stream>>>(points, features, out,
                                                             N, H, W, tiles_x);
}